// Round 8
// baseline (969.723 us; speedup 1.0000x reference)
//
#include <hip/hip_runtime.h>
#include <math.h>

#define BB 32
#define CC 256
#define HWt 1024          // H*W
#define NN 32768          // B*H*W
#define KK 2048
#define RQDEPTH 4
#define CAP 64            // candidate list capacity per row (overflow -> full rescan)
#define DELTA 4e-3f       // H-only window; rigorous need ~1.6e-3 (2.5x margin)

typedef __attribute__((ext_vector_type(8))) short short8;     // 8 bf16 (4 VGPR)
typedef __attribute__((ext_vector_type(16))) float f32x16;    // MFMA 32x32 acc

// ===== numpy pairwise sum-of-squares, blocksize-128 tree, bit-exact =====
__device__ __forceinline__ float pw128sq(const float4* __restrict__ a4) {
  float r[8];
  {
    float4 p = a4[0], q = a4[1];
    r[0] = __fmul_rn(p.x, p.x); r[1] = __fmul_rn(p.y, p.y);
    r[2] = __fmul_rn(p.z, p.z); r[3] = __fmul_rn(p.w, p.w);
    r[4] = __fmul_rn(q.x, q.x); r[5] = __fmul_rn(q.y, q.y);
    r[6] = __fmul_rn(q.z, q.z); r[7] = __fmul_rn(q.w, q.w);
  }
  for (int i = 1; i < 16; ++i) {
    float4 p = a4[2 * i], q = a4[2 * i + 1];
    r[0] = __fadd_rn(r[0], __fmul_rn(p.x, p.x));
    r[1] = __fadd_rn(r[1], __fmul_rn(p.y, p.y));
    r[2] = __fadd_rn(r[2], __fmul_rn(p.z, p.z));
    r[3] = __fadd_rn(r[3], __fmul_rn(p.w, p.w));
    r[4] = __fadd_rn(r[4], __fmul_rn(q.x, q.x));
    r[5] = __fadd_rn(r[5], __fmul_rn(q.y, q.y));
    r[6] = __fadd_rn(r[6], __fmul_rn(q.z, q.z));
    r[7] = __fadd_rn(r[7], __fmul_rn(q.w, q.w));
  }
  return __fadd_rn(__fadd_rn(__fadd_rn(r[0], r[1]), __fadd_rn(r[2], r[3])),
                   __fadd_rn(__fadd_rn(r[4], r[5]), __fadd_rn(r[6], r[7])));
}

// bf16 round-to-nearest-even (finite inputs)
__device__ __forceinline__ unsigned short f2bf(float x) {
  unsigned u = __float_as_uint(x);
  return (unsigned short)((u + 0x7fffu + ((u >> 16) & 1u)) >> 16);
}
// monotone float<->uint order-preserving encode (for atomicMin on float)
__device__ __forceinline__ unsigned fenc(float f) {
  unsigned u = __float_as_uint(f);
  return (u & 0x80000000u) ? ~u : (u | 0x80000000u);
}
__device__ __forceinline__ float fdec(unsigned k) {
  return __uint_as_float((k & 0x80000000u) ? (k ^ 0x80000000u) : ~k);
}

// exact per-(n,k) fp32 path, byte-identical to the verified kernel:
// strict c-ascending fmaf chain; caller applies fl(A+B) - 2M.
__device__ __forceinline__ float exact_dot(const float4* __restrict__ zr4,
                                           const float4* __restrict__ e4) {
  float a = 0.f;
#pragma unroll 8
  for (int c4 = 0; c4 < 64; ++c4) {
    const float4 z4 = zr4[c4];
    const float4 q4 = e4[c4];
    a = fmaf(z4.x, q4.x, a);
    a = fmaf(z4.y, q4.y, a);
    a = fmaf(z4.z, q4.z, a);
    a = fmaf(z4.w, q4.w, a);
  }
  return a;
}

// ---------------- prep: z [B,C,H,W] -> resid [N,C] ----------------
__global__ void k_ztrans(const float* __restrict__ z, float* __restrict__ resid) {
  __shared__ float tile[32][33];
  int b = blockIdx.z, c0 = blockIdx.y * 32, hw0 = blockIdx.x * 32;
  int tx = threadIdx.x & 31, ty = threadIdx.x >> 5;
  for (int i = ty; i < 32; i += 8)
    tile[i][tx] = z[((size_t)b * CC + c0 + i) * HWt + hw0 + tx];
  __syncthreads();
  for (int i = ty; i < 32; i += 8)
    resid[((size_t)b * HWt + hw0 + i) * CC + c0 + tx] = tile[tx][i];
}

// ---------------- prep: codebook bf16 H in MFMA B-fragment order ------
// esH8[(kt*32 + c8)*32 + col] = 8 bf16 at c = c8*8 + i for codeword k = kt*32+col.
__global__ void k_esplitH(const float* __restrict__ cb, short8* __restrict__ esH8) {
  const int tg = blockIdx.x * 256 + threadIdx.x;   // 65536 = 2048 k * 32 c8
  const int k = tg >> 5, c8 = tg & 31;
  const int idx8 = ((k >> 5) * 32 + c8) * 32 + (k & 31);
  const float4* s4 = (const float4*)(cb + (size_t)k * CC + c8 * 8);
  float4 p = s4[0], q = s4[1];
  short8 H;
  H[0] = (short)f2bf(p.x); H[1] = (short)f2bf(p.y);
  H[2] = (short)f2bf(p.z); H[3] = (short)f2bf(p.w);
  H[4] = (short)f2bf(q.x); H[5] = (short)f2bf(q.y);
  H[6] = (short)f2bf(q.z); H[7] = (short)f2bf(q.w);
  esH8[idx8] = H;
}

// ---------------- B_k = np.sum(cb**2, axis=1) bit-exact ----------------
__global__ void k_bnorm(const float* __restrict__ cb, float* __restrict__ Bcol) {
  int k = blockIdx.x * 256 + threadIdx.x;
  if (k >= KK) return;
  const float4* row = (const float4*)(cb + (size_t)k * CC);
  Bcol[k] = __fadd_rn(pw128sq(row), pw128sq(row + 32));
}

// ---------------- A_n = np.sum(resid**2, axis=1) bit-exact ----------------
__global__ void k_anorm(const float* __restrict__ resid, float* __restrict__ Arow) {
  int n = blockIdx.x * 256 + threadIdx.x;
  if (n >= NN) return;
  const float4* row = (const float4*)(resid + (size_t)n * CC);
  Arow[n] = __fadd_rn(pw128sq(row), pw128sq(row + 32));
}

__global__ void k_zero(int* counts) {
  int t = blockIdx.x * 256 + threadIdx.x;
  if (t < KK) counts[t] = 0;
}

// ---------------- bulk: MFMA-pruned exact argmin (H-only filter) ----------
// Phase 1 (MFMA): M~ = xh*eh (single bf16 MFMA per step); d~ = B - 2M~.
//   |d~ - d_true| <= Sum|x_c e_c| * 2^-7 + accum <= sqrt(A*B)*2^-7 ~= 7.5e-4.
//   Soundness: ref winner k* has d~(k*) <= d~min + 2*eps_m + 2*eps_chain
//   ~= 1.6e-3 << DELTA=4e-3. Threshold atomicMin is stale-high = superset.
//   CAP overflow -> full-K rescan for that row (correctness unconditional).
// Phase 2 (exact): byte-identical fp32 chain (strict c-ascending fmaf,
//   fl(A+B) - 2M, u64 (dist,k) lex-min) over the candidate superset.
__global__ __launch_bounds__(512, 8) void k_bulk(
    const float* __restrict__ resid, const short8* __restrict__ esH8,
    const float* __restrict__ cb, const float* __restrict__ Arow,
    const float* __restrict__ Bcol, int* __restrict__ idxAll,
    float* __restrict__ idxOut, int* __restrict__ counts, int depth) {
  __shared__ short8 zH8[32 * 32];          // [c8][row], 16 KB
  __shared__ int cnt[32];
  __shared__ unsigned minkey[32];
  __shared__ unsigned long long best[32];
  __shared__ int clist[32 * CAP];          // 8 KB

  const int t = threadIdx.x;
  const int row0 = blockIdx.x * 32;

  if (t < 32) { cnt[t] = 0; minkey[t] = 0xFFFFFFFFu; best[t] = ~0ull; }

  // ---- bf16 H-split of z tile directly from global, A-fragment layout ----
  {
    const int srow = t & 31;
    const int c8a = (t >> 5) * 2;
#pragma unroll
    for (int cc = 0; cc < 2; ++cc) {
      const int c8 = c8a + cc;
      const float4* s4 =
          (const float4*)(resid + (size_t)(row0 + srow) * CC + c8 * 8);
      float4 p = s4[0], q = s4[1];
      short8 H;
      H[0] = (short)f2bf(p.x); H[1] = (short)f2bf(p.y);
      H[2] = (short)f2bf(p.z); H[3] = (short)f2bf(p.w);
      H[4] = (short)f2bf(q.x); H[5] = (short)f2bf(q.y);
      H[6] = (short)f2bf(q.z); H[7] = (short)f2bf(q.w);
      zH8[c8 * 32 + srow] = H;             // lane-consecutive 16B: conflict-free
    }
  }
  __syncthreads();

  const int wave = t >> 6, lane = t & 63;
  const int l31 = lane & 31, hh = lane >> 5;

#define LOADF(AH, EH, STEP)                                                    \
  { const int o_ = ((STEP) * 2 + hh) * 32 + l31;                               \
    AH = zH8[o_]; EH = esH8[kt * 1024 + o_]; }

#pragma unroll 1
  for (int it = 0; it < 8; ++it) {
    const int kt = wave * 8 + it, kb = kt * 32;
    f32x16 a0;
#pragma unroll
    for (int i = 0; i < 16; ++i) a0[i] = 0.f;

    short8 cah, ceh, nah, neh;
    LOADF(cah, ceh, 0)
#pragma unroll
    for (int step = 0; step < 16; ++step) {
      if (step < 15) LOADF(nah, neh, step + 1)
      a0 = __builtin_amdgcn_mfma_f32_32x32x16_bf16(cah, ceh, a0, 0, 0, 0);
      __builtin_amdgcn_sched_barrier(0);   // liveness fence: <=2 frag sets live
      if (step < 15) { cah = nah; ceh = neh; }
    }

    const float bkv = Bcol[kb + l31];
    float dt[16];
#pragma unroll
    for (int r = 0; r < 16; ++r) {
      const float m = a0[r];
      dt[r] = __fsub_rn(bkv, __fadd_rn(m, m));
    }
    if (it == 0) {
      // seed per-row min (finite thresholds before any append test)
#pragma unroll
      for (int r = 0; r < 16; ++r) {
        float rm = dt[r];
#pragma unroll
        for (int m = 1; m < 32; m <<= 1) rm = fminf(rm, __shfl_xor(rm, m));
        if (l31 == 0) {
          const int rowr = (r & 3) + 8 * (r >> 2) + 4 * hh;
          atomicMin(&minkey[rowr], fenc(rm));
        }
      }
    }
#pragma unroll
    for (int r = 0; r < 16; ++r) {
      const int rowr = (r & 3) + 8 * (r >> 2) + 4 * hh;
      const float thr = fdec(minkey[rowr]) + DELTA;   // stale-high = superset
      if (dt[r] <= thr) {
        atomicMin(&minkey[rowr], fenc(dt[r]));
        int idx = atomicAdd(&cnt[rowr], 1);
        if (idx < CAP) clist[rowr * CAP + idx] = kb + l31;
      }
    }
  }
  __syncthreads();

  // ---- exact recheck of candidates (byte-identical fp32 path) ----
  {
    const int row = t >> 4;
    const int nc0 = cnt[row];
    const float av = Arow[row0 + row];
    const float4* zr4 = (const float4*)(resid + (size_t)(row0 + row) * CC);
    if (nc0 <= CAP) {
      for (int s = (t & 15); s < nc0; s += 16) {
        const int k = clist[row * CAP + s];
        const float a = exact_dot(zr4, (const float4*)(cb + (size_t)k * CC));
        const float Cv = __fadd_rn(av, Bcol[k]);            // fl32(A + B)
        const float sv = __fsub_rn(Cv, __fadd_rn(a, a));    // fl32(C - 2M)
        unsigned long long pk =
            ((unsigned long long)__float_as_uint(sv) << 32) | (unsigned)k;
        atomicMin(&best[row], pk);
      }
    } else {
      // overflow fallback (statistically ~never): exact scan of all K
      for (int k = (t & 15); k < KK; k += 16) {
        const float a = exact_dot(zr4, (const float4*)(cb + (size_t)k * CC));
        const float Cv = __fadd_rn(av, Bcol[k]);
        const float sv = __fsub_rn(Cv, __fadd_rn(a, a));
        unsigned long long pk =
            ((unsigned long long)__float_as_uint(sv) << 32) | (unsigned)k;
        atomicMin(&best[row], pk);
      }
    }
  }
  __syncthreads();
  if (t < 32) {
    const int wi = (int)(unsigned)(best[t] & 0xffffffffu);
    const int n = row0 + t;
    idxAll[depth * NN + n] = wi;
    idxOut[n] = (float)wi;
    atomicAdd(counts + wi, 1);
  }
}

// ------- update: resid -= q (fp32, np order), cum[d] = cum[d-1] + q, zst at d=3 -------
__global__ void k_update(const float* __restrict__ cb, const int* __restrict__ idxAll,
                         float* __restrict__ resid, float* __restrict__ cum,
                         float* __restrict__ zst, int depth) {
  __shared__ float qt[32][33];
  __shared__ float rt[32][33];
  int b = blockIdx.z, c0 = blockIdx.y * 32, hw0 = blockIdx.x * 32;
  int tx = threadIdx.x & 31, ty = threadIdx.x >> 5;
  const int* idx = idxAll + depth * NN;
  for (int i = ty; i < 32; i += 8) {
    int n = b * HWt + hw0 + i;
    int kk = idx[n];
    size_t fo = (size_t)n * CC + c0 + tx;
    float q = cb[(size_t)kk * CC + c0 + tx];
    float r = __fsub_rn(resid[fo], q);
    resid[fo] = r;
    qt[i][tx] = q;
    rt[i][tx] = r;
  }
  __syncthreads();
  const size_t PLANE = (size_t)NN * CC;
  for (int i = ty; i < 32; i += 8) {
    size_t oo = ((size_t)b * CC + c0 + i) * HWt + hw0 + tx;
    float q = qt[tx][i];
    float prevv = (depth == 0) ? 0.f : cum[(size_t)(depth - 1) * PLANE + oo];
    cum[(size_t)depth * PLANE + oo] = __fadd_rn(prevv, q);
    if (depth == 3) zst[oo] = rt[tx][i];
  }
}

// ---------------- perplexity ----------------
__global__ void k_perp(const int* __restrict__ counts, float* __restrict__ out) {
  __shared__ double sh[256];
  double s = 0.0;
  for (int k = threadIdx.x; k < KK; k += 256) {
    int c = counts[k];
    if (c > 0) {
      double p = (double)c / (double)(RQDEPTH * NN);
      s += p * log(p);
    }
  }
  sh[threadIdx.x] = s;
  __syncthreads();
  for (int st = 128; st; st >>= 1) {
    if (threadIdx.x < st) sh[threadIdx.x] += sh[threadIdx.x + st];
    __syncthreads();
  }
  if (threadIdx.x == 0) out[0] = (float)exp(-sh[0]);
}

extern "C" void kernel_launch(void* const* d_in, const int* in_sizes, int n_in,
                              void* d_out, int out_size, void* d_ws, size_t ws_size,
                              hipStream_t stream) {
  const float* z  = (const float*)d_in[0];
  const float* cb = (const float*)d_in[1];
  float* out = (float*)d_out;
  const size_t PLANE = (size_t)NN * CC;          // 8,388,608
  float* cum  = out;                             // [4][B][C][H][W]
  float* zst  = out + (size_t)RQDEPTH * PLANE;   // [B][C][H][W]
  float* idxo = zst + PLANE;                     // [4][N]
  float* perp = idxo + (size_t)RQDEPTH * NN;     // scalar

  float* resid = (float*)d_ws;                   // N*C floats
  float* esbase = resid + PLANE;                 // 2 MB region (old cbT slot)
  short8* esH8 = (short8*)esbase;                // 1 MB: 65536 short8
  float* Arow  = esbase + (size_t)CC * KK;       // N
  float* Bcol  = Arow + NN;                      // K
  int* idxAll  = (int*)(Bcol + KK);              // D*N
  int* counts  = idxAll + RQDEPTH * NN;          // K

  dim3 tgrid(HWt / 32, CC / 32, BB);             // 32 x 8 x 32
  k_ztrans<<<tgrid, 256, 0, stream>>>(z, resid);
  k_esplitH<<<256, 256, 0, stream>>>(cb, esH8);
  k_bnorm<<<KK / 256, 256, 0, stream>>>(cb, Bcol);
  k_zero<<<(KK + 255) / 256, 256, 0, stream>>>(counts);

  for (int d = 0; d < RQDEPTH; ++d) {
    k_anorm<<<NN / 256, 256, 0, stream>>>(resid, Arow);
    k_bulk<<<NN / 32, 512, 0, stream>>>(resid, esH8, cb, Arow, Bcol,
                                        idxAll, idxo + (size_t)d * NN, counts, d);
    k_update<<<tgrid, 256, 0, stream>>>(cb, idxAll, resid, cum, zst, d);
  }
  k_perp<<<1, 256, 0, stream>>>(counts, perp);
}

// Round 9
// 964.113 us; speedup vs baseline: 1.0058x; 1.0058x over previous
//
#include <hip/hip_runtime.h>
#include <math.h>

#define BB 32
#define CC 256
#define HWt 1024          // H*W
#define NN 32768          // B*H*W
#define KK 2048
#define RQDEPTH 4
#define CAP 64            // candidate list capacity per row (overflow -> full rescan)
#define DELTA 4e-3f       // H-only window; rigorous need ~1.6e-3 (2.5x margin)

typedef __attribute__((ext_vector_type(8))) short short8;     // 8 bf16 (4 VGPR)
typedef __attribute__((ext_vector_type(16))) float f32x16;    // MFMA 32x32 acc

// ===== numpy pairwise sum-of-squares, blocksize-128 tree, bit-exact =====
__device__ __forceinline__ float pw128sq(const float4* __restrict__ a4) {
  float r[8];
  {
    float4 p = a4[0], q = a4[1];
    r[0] = __fmul_rn(p.x, p.x); r[1] = __fmul_rn(p.y, p.y);
    r[2] = __fmul_rn(p.z, p.z); r[3] = __fmul_rn(p.w, p.w);
    r[4] = __fmul_rn(q.x, q.x); r[5] = __fmul_rn(q.y, q.y);
    r[6] = __fmul_rn(q.z, q.z); r[7] = __fmul_rn(q.w, q.w);
  }
  for (int i = 1; i < 16; ++i) {
    float4 p = a4[2 * i], q = a4[2 * i + 1];
    r[0] = __fadd_rn(r[0], __fmul_rn(p.x, p.x));
    r[1] = __fadd_rn(r[1], __fmul_rn(p.y, p.y));
    r[2] = __fadd_rn(r[2], __fmul_rn(p.z, p.z));
    r[3] = __fadd_rn(r[3], __fmul_rn(p.w, p.w));
    r[4] = __fadd_rn(r[4], __fmul_rn(q.x, q.x));
    r[5] = __fadd_rn(r[5], __fmul_rn(q.y, q.y));
    r[6] = __fadd_rn(r[6], __fmul_rn(q.z, q.z));
    r[7] = __fadd_rn(r[7], __fmul_rn(q.w, q.w));
  }
  return __fadd_rn(__fadd_rn(__fadd_rn(r[0], r[1]), __fadd_rn(r[2], r[3])),
                   __fadd_rn(__fadd_rn(r[4], r[5]), __fadd_rn(r[6], r[7])));
}

// bf16 round-to-nearest-even (finite inputs)
__device__ __forceinline__ unsigned short f2bf(float x) {
  unsigned u = __float_as_uint(x);
  return (unsigned short)((u + 0x7fffu + ((u >> 16) & 1u)) >> 16);
}
// monotone float<->uint order-preserving encode (for atomicMin on float)
__device__ __forceinline__ unsigned fenc(float f) {
  unsigned u = __float_as_uint(f);
  return (u & 0x80000000u) ? ~u : (u | 0x80000000u);
}
__device__ __forceinline__ float fdec(unsigned k) {
  return __uint_as_float((k & 0x80000000u) ? (k ^ 0x80000000u) : ~k);
}

// exact per-(n,k) fp32 path, byte-identical to the verified kernel:
// strict c-ascending fmaf chain; caller applies fl(A+B) - 2M.
__device__ __forceinline__ float exact_dot(const float4* __restrict__ zr4,
                                           const float4* __restrict__ e4) {
  float a = 0.f;
#pragma unroll 8
  for (int c4 = 0; c4 < 64; ++c4) {
    const float4 z4 = zr4[c4];
    const float4 q4 = e4[c4];
    a = fmaf(z4.x, q4.x, a);
    a = fmaf(z4.y, q4.y, a);
    a = fmaf(z4.z, q4.z, a);
    a = fmaf(z4.w, q4.w, a);
  }
  return a;
}

// ---------------- prep: z [B,C,H,W] -> resid [N,C] ----------------
__global__ void k_ztrans(const float* __restrict__ z, float* __restrict__ resid) {
  __shared__ float tile[32][33];
  int b = blockIdx.z, c0 = blockIdx.y * 32, hw0 = blockIdx.x * 32;
  int tx = threadIdx.x & 31, ty = threadIdx.x >> 5;
  for (int i = ty; i < 32; i += 8)
    tile[i][tx] = z[((size_t)b * CC + c0 + i) * HWt + hw0 + tx];
  __syncthreads();
  for (int i = ty; i < 32; i += 8)
    resid[((size_t)b * HWt + hw0 + i) * CC + c0 + tx] = tile[tx][i];
}

// ---------------- prep: codebook bf16 H in MFMA B-fragment order ------
// esH8[(kt*32 + c8)*32 + col] = 8 bf16 at c = c8*8 + i for codeword k = kt*32+col.
__global__ void k_esplitH(const float* __restrict__ cb, short8* __restrict__ esH8) {
  const int tg = blockIdx.x * 256 + threadIdx.x;   // 65536 = 2048 k * 32 c8
  const int k = tg >> 5, c8 = tg & 31;
  const int idx8 = ((k >> 5) * 32 + c8) * 32 + (k & 31);
  const float4* s4 = (const float4*)(cb + (size_t)k * CC + c8 * 8);
  float4 p = s4[0], q = s4[1];
  short8 H;
  H[0] = (short)f2bf(p.x); H[1] = (short)f2bf(p.y);
  H[2] = (short)f2bf(p.z); H[3] = (short)f2bf(p.w);
  H[4] = (short)f2bf(q.x); H[5] = (short)f2bf(q.y);
  H[6] = (short)f2bf(q.z); H[7] = (short)f2bf(q.w);
  esH8[idx8] = H;
}

// ---------------- B_k = np.sum(cb**2, axis=1) bit-exact ----------------
__global__ void k_bnorm(const float* __restrict__ cb, float* __restrict__ Bcol) {
  int k = blockIdx.x * 256 + threadIdx.x;
  if (k >= KK) return;
  const float4* row = (const float4*)(cb + (size_t)k * CC);
  Bcol[k] = __fadd_rn(pw128sq(row), pw128sq(row + 32));
}

// ---------------- A_n = np.sum(resid**2, axis=1) bit-exact ----------------
__global__ void k_anorm(const float* __restrict__ resid, float* __restrict__ Arow) {
  int n = blockIdx.x * 256 + threadIdx.x;
  if (n >= NN) return;
  const float4* row = (const float4*)(resid + (size_t)n * CC);
  Arow[n] = __fadd_rn(pw128sq(row), pw128sq(row + 32));
}

__global__ void k_zero(int* counts) {
  int t = blockIdx.x * 256 + threadIdx.x;
  if (t < KK) counts[t] = 0;
}

// ---------------- bulk: MFMA-pruned exact argmin (H-only filter) ----------
// Round-8 numerics exactly (H-only bf16 MFMA filter, DELTA window, CAP
// overflow -> full rescan, byte-identical fp32 recheck). Schedule rebuilt
// around the round-8 finding (dur insensitive to work AND occupancy => the
// bottleneck was 128 serialized vmcnt-drain round-trips per wave, inflated by
// all blocks marching the same es lines in lockstep):
//  * es loads batched 8-deep (two batches of 8 dwordx4 per kt tile) -> 16
//    amortized waits per wave instead of 128 full drains. No sched_barrier.
//  * wave's 16 z-fragments hoisted into registers once (reused across all
//    8 kt tiles) -> zero ds_reads in the inner loop.
//  * per-block kt rotation ((it + blockIdx.x) & 7) de-lockstops the cross-
//    block es line convoys (scan order is irrelevant to a min).
__global__ __launch_bounds__(512, 4) void k_bulk(
    const float* __restrict__ resid, const short8* __restrict__ esH8,
    const float* __restrict__ cb, const float* __restrict__ Arow,
    const float* __restrict__ Bcol, int* __restrict__ idxAll,
    float* __restrict__ idxOut, int* __restrict__ counts, int depth) {
  __shared__ short8 zH8[32 * 32];          // [c8][row], 16 KB
  __shared__ int cnt[32];
  __shared__ unsigned minkey[32];
  __shared__ unsigned long long best[32];
  __shared__ int clist[32 * CAP];          // 8 KB

  const int t = threadIdx.x;
  const int row0 = blockIdx.x * 32;

  if (t < 32) { cnt[t] = 0; minkey[t] = 0xFFFFFFFFu; best[t] = ~0ull; }

  // ---- bf16 H-split of z tile directly from global, A-fragment layout ----
  {
    const int srow = t & 31;
    const int c8a = (t >> 5) * 2;
#pragma unroll
    for (int cc = 0; cc < 2; ++cc) {
      const int c8 = c8a + cc;
      const float4* s4 =
          (const float4*)(resid + (size_t)(row0 + srow) * CC + c8 * 8);
      float4 p = s4[0], q = s4[1];
      short8 H;
      H[0] = (short)f2bf(p.x); H[1] = (short)f2bf(p.y);
      H[2] = (short)f2bf(p.z); H[3] = (short)f2bf(p.w);
      H[4] = (short)f2bf(q.x); H[5] = (short)f2bf(q.y);
      H[6] = (short)f2bf(q.z); H[7] = (short)f2bf(q.w);
      zH8[c8 * 32 + srow] = H;             // lane-consecutive 16B: conflict-free
    }
  }
  __syncthreads();

  const int wave = t >> 6, lane = t & 63;
  const int l31 = lane & 31, hh = lane >> 5;

  // hoist this wave's 16 z-fragments to registers (64 VGPR, reused 8x)
  short8 zr[16];
  {
    const short8* zb = zH8 + hh * 32 + l31;
#pragma unroll
    for (int s = 0; s < 16; ++s) zr[s] = zb[s * 64];
  }

#pragma unroll 1
  for (int it = 0; it < 8; ++it) {
    const int kt = wave * 8 + ((it + (int)blockIdx.x) & 7);   // de-lockstep
    const int kb = kt * 32;
    f32x16 a0;
#pragma unroll
    for (int i = 0; i < 16; ++i) a0[i] = 0.f;

    const short8* ep = esH8 + kt * 1024 + hh * 32 + l31;
#pragma unroll
    for (int half = 0; half < 2; ++half) {
      short8 e[8];
#pragma unroll
      for (int s = 0; s < 8; ++s) e[s] = ep[(half * 8 + s) * 64];  // 8 in flight
#pragma unroll
      for (int s = 0; s < 8; ++s)
        a0 = __builtin_amdgcn_mfma_f32_32x32x16_bf16(zr[half * 8 + s], e[s],
                                                     a0, 0, 0, 0);
    }

    const float bkv = Bcol[kb + l31];
    float dt[16];
#pragma unroll
    for (int r = 0; r < 16; ++r) {
      const float m = a0[r];
      dt[r] = __fsub_rn(bkv, __fadd_rn(m, m));
    }
    if (it == 0) {
      // seed per-row min (finite thresholds before any append test)
#pragma unroll
      for (int r = 0; r < 16; ++r) {
        float rm = dt[r];
#pragma unroll
        for (int m = 1; m < 32; m <<= 1) rm = fminf(rm, __shfl_xor(rm, m));
        if (l31 == 0) {
          const int rowr = (r & 3) + 8 * (r >> 2) + 4 * hh;
          atomicMin(&minkey[rowr], fenc(rm));
        }
      }
    }
#pragma unroll
    for (int r = 0; r < 16; ++r) {
      const int rowr = (r & 3) + 8 * (r >> 2) + 4 * hh;
      const float thr = fdec(minkey[rowr]) + DELTA;   // stale-high = superset
      if (dt[r] <= thr) {
        atomicMin(&minkey[rowr], fenc(dt[r]));
        int idx = atomicAdd(&cnt[rowr], 1);
        if (idx < CAP) clist[rowr * CAP + idx] = kb + l31;
      }
    }
  }
  __syncthreads();

  // ---- exact recheck of candidates (byte-identical fp32 path) ----
  {
    const int row = t >> 4;
    const int nc0 = cnt[row];
    const float av = Arow[row0 + row];
    const float4* zr4 = (const float4*)(resid + (size_t)(row0 + row) * CC);
    if (nc0 <= CAP) {
      for (int s = (t & 15); s < nc0; s += 16) {
        const int k = clist[row * CAP + s];
        const float a = exact_dot(zr4, (const float4*)(cb + (size_t)k * CC));
        const float Cv = __fadd_rn(av, Bcol[k]);            // fl32(A + B)
        const float sv = __fsub_rn(Cv, __fadd_rn(a, a));    // fl32(C - 2M)
        unsigned long long pk =
            ((unsigned long long)__float_as_uint(sv) << 32) | (unsigned)k;
        atomicMin(&best[row], pk);
      }
    } else {
      // overflow fallback (statistically ~never): exact scan of all K
      for (int k = (t & 15); k < KK; k += 16) {
        const float a = exact_dot(zr4, (const float4*)(cb + (size_t)k * CC));
        const float Cv = __fadd_rn(av, Bcol[k]);
        const float sv = __fsub_rn(Cv, __fadd_rn(a, a));
        unsigned long long pk =
            ((unsigned long long)__float_as_uint(sv) << 32) | (unsigned)k;
        atomicMin(&best[row], pk);
      }
    }
  }
  __syncthreads();
  if (t < 32) {
    const int wi = (int)(unsigned)(best[t] & 0xffffffffu);
    const int n = row0 + t;
    idxAll[depth * NN + n] = wi;
    idxOut[n] = (float)wi;
    atomicAdd(counts + wi, 1);
  }
}

// ------- update: resid -= q (fp32, np order), cum[d] = cum[d-1] + q, zst at d=3 -------
__global__ void k_update(const float* __restrict__ cb, const int* __restrict__ idxAll,
                         float* __restrict__ resid, float* __restrict__ cum,
                         float* __restrict__ zst, int depth) {
  __shared__ float qt[32][33];
  __shared__ float rt[32][33];
  int b = blockIdx.z, c0 = blockIdx.y * 32, hw0 = blockIdx.x * 32;
  int tx = threadIdx.x & 31, ty = threadIdx.x >> 5;
  const int* idx = idxAll + depth * NN;
  for (int i = ty; i < 32; i += 8) {
    int n = b * HWt + hw0 + i;
    int kk = idx[n];
    size_t fo = (size_t)n * CC + c0 + tx;
    float q = cb[(size_t)kk * CC + c0 + tx];
    float r = __fsub_rn(resid[fo], q);
    resid[fo] = r;
    qt[i][tx] = q;
    rt[i][tx] = r;
  }
  __syncthreads();
  const size_t PLANE = (size_t)NN * CC;
  for (int i = ty; i < 32; i += 8) {
    size_t oo = ((size_t)b * CC + c0 + i) * HWt + hw0 + tx;
    float q = qt[tx][i];
    float prevv = (depth == 0) ? 0.f : cum[(size_t)(depth - 1) * PLANE + oo];
    cum[(size_t)depth * PLANE + oo] = __fadd_rn(prevv, q);
    if (depth == 3) zst[oo] = rt[tx][i];
  }
}

// ---------------- perplexity ----------------
__global__ void k_perp(const int* __restrict__ counts, float* __restrict__ out) {
  __shared__ double sh[256];
  double s = 0.0;
  for (int k = threadIdx.x; k < KK; k += 256) {
    int c = counts[k];
    if (c > 0) {
      double p = (double)c / (double)(RQDEPTH * NN);
      s += p * log(p);
    }
  }
  sh[threadIdx.x] = s;
  __syncthreads();
  for (int st = 128; st; st >>= 1) {
    if (threadIdx.x < st) sh[threadIdx.x] += sh[threadIdx.x + st];
    __syncthreads();
  }
  if (threadIdx.x == 0) out[0] = (float)exp(-sh[0]);
}

extern "C" void kernel_launch(void* const* d_in, const int* in_sizes, int n_in,
                              void* d_out, int out_size, void* d_ws, size_t ws_size,
                              hipStream_t stream) {
  const float* z  = (const float*)d_in[0];
  const float* cb = (const float*)d_in[1];
  float* out = (float*)d_out;
  const size_t PLANE = (size_t)NN * CC;          // 8,388,608
  float* cum  = out;                             // [4][B][C][H][W]
  float* zst  = out + (size_t)RQDEPTH * PLANE;   // [B][C][H][W]
  float* idxo = zst + PLANE;                     // [4][N]
  float* perp = idxo + (size_t)RQDEPTH * NN;     // scalar

  float* resid = (float*)d_ws;                   // N*C floats
  float* esbase = resid + PLANE;                 // 2 MB region (old cbT slot)
  short8* esH8 = (short8*)esbase;                // 1 MB: 65536 short8
  float* Arow  = esbase + (size_t)CC * KK;       // N
  float* Bcol  = Arow + NN;                      // K
  int* idxAll  = (int*)(Bcol + KK);              // D*N
  int* counts  = idxAll + RQDEPTH * NN;          // K

  dim3 tgrid(HWt / 32, CC / 32, BB);             // 32 x 8 x 32
  k_ztrans<<<tgrid, 256, 0, stream>>>(z, resid);
  k_esplitH<<<256, 256, 0, stream>>>(cb, esH8);
  k_bnorm<<<KK / 256, 256, 0, stream>>>(cb, Bcol);
  k_zero<<<(KK + 255) / 256, 256, 0, stream>>>(counts);

  for (int d = 0; d < RQDEPTH; ++d) {
    k_anorm<<<NN / 256, 256, 0, stream>>>(resid, Arow);
    k_bulk<<<NN / 32, 512, 0, stream>>>(resid, esH8, cb, Arow, Bcol,
                                        idxAll, idxo + (size_t)d * NN, counts, d);
    k_update<<<tgrid, 256, 0, stream>>>(cb, idxAll, resid, cum, zst, d);
  }
  k_perp<<<1, 256, 0, stream>>>(counts, perp);
}